// Round 3
// baseline (6454.094 us; speedup 1.0000x reference)
//
#include <hip/hip_runtime.h>
#include <hip/hip_cooperative_groups.h>

namespace cg = cooperative_groups;

typedef unsigned short ushort_t;
typedef __attribute__((ext_vector_type(4))) float f32x4;
typedef __attribute__((ext_vector_type(8))) short s16x8;
typedef __attribute__((ext_vector_type(4))) unsigned short u16x4;
typedef __attribute__((ext_vector_type(8))) __bf16 bf16x8;

#define DEV __device__ __forceinline__

DEV float bf2f(ushort_t u){ union { unsigned int i; float f; } v; v.i = ((unsigned int)u) << 16; return v.f; }
DEV ushort_t f2bf(float f){
  union { float f; unsigned int i; } v; v.f = f;
  unsigned int r = v.i + 0x7FFFu + ((v.i >> 16) & 1u);   // RNE
  return (ushort_t)(r >> 16);
}
DEV float frcp(float x){
#if __has_builtin(__builtin_amdgcn_rcpf)
  return __builtin_amdgcn_rcpf(x);
#else
  return 1.0f / x;
#endif
}
DEV float fast_tanh(float x){
  x = fminf(9.0f, fmaxf(-9.0f, x));
  float e = __expf(2.0f * x);
  return fmaf(-2.0f, frcp(e + 1.0f), 1.0f);
}
DEV float fast_sig(float x){ return frcp(1.0f + __expf(-x)); }

DEV f32x4 mfma16(s16x8 a, s16x8 b, f32x4 c){
  return __builtin_amdgcn_mfma_f32_16x16x32_bf16(
      __builtin_bit_cast(bf16x8, a), __builtin_bit_cast(bf16x8, b), c, 0, 0, 0);
}

// ---------------------------------------------------------------------------
// Generic B^T GEMM (one-shot uses only): C[m,n] = sum_k A[m,k]*B[n,k].
// MODE 0: A=h f32 [16384,1024], B=W_attn2 f32 -> z2 bf16 (+b_attn1[n]+b_attn2[n])
// MODE 2: A=dct bf16 [256,2048], B=W_fc1 f32 [1024,2048] -> out f32 [256,1024]
// ---------------------------------------------------------------------------
template<int MODE>
__global__ __launch_bounds__(256) void gemm_bt_k(
    const void* __restrict__ Ap, const void* __restrict__ Bp, const void* __restrict__ B2p,
    void* __restrict__ Cp, const float* __restrict__ bias1, const float* __restrict__ bias2)
{
  const int bm0 = blockIdx.x * 64;
  const int bn0 = blockIdx.y * 64;
  const int tid = threadIdx.x;
  const int srow = tid >> 2, sseg = tid & 3;
  const int wid = tid >> 6, lane = tid & 63;
  const int wr = wid >> 1, wc = wid & 1;
  const int fr = lane & 15, kseg = lane >> 4;

  int K;
  const float* Af = nullptr; const ushort_t* Ab = nullptr;
  const float* Bf = nullptr;
  if constexpr (MODE == 0) {
    K = 1024;
    Af = (const float*)Ap + (size_t)(bm0 + srow) * 1024;
    Bf = (const float*)Bp + (size_t)(bn0 + srow) * 1024;
  } else {
    K = 2048;
    Ab = (const ushort_t*)Ap + (size_t)(bm0 + srow) * 2048;
    Bf = (const float*)Bp + (size_t)(bn0 + srow) * 2048;
  }
  (void)B2p;

  __shared__ ushort_t As[64 * 32];
  __shared__ ushort_t Bs[64 * 32];
  f32x4 acc00 = {0,0,0,0}, acc01 = {0,0,0,0}, acc10 = {0,0,0,0}, acc11 = {0,0,0,0};

  const int sstore = srow * 32 + ((sseg ^ (srow & 3)) << 3);
  const int ar0 = wr * 32 + fr,      ar1 = wr * 32 + 16 + fr;
  const int br0 = wc * 32 + fr,      br1 = wc * 32 + 16 + fr;
  const int aoff0 = ar0 * 32 + ((kseg ^ (ar0 & 3)) << 3);
  const int aoff1 = ar1 * 32 + ((kseg ^ (ar1 & 3)) << 3);
  const int boff0 = br0 * 32 + ((kseg ^ (br0 & 3)) << 3);
  const int boff1 = br1 * 32 + ((kseg ^ (br1 & 3)) << 3);

  for (int k0 = 0; k0 < K; k0 += 32) {
    s16x8 av, bv;
    if constexpr (MODE == 0) {
      const float* p = Af + k0 + sseg * 8;
      f32x4 x0 = *(const f32x4*)p, x1 = *(const f32x4*)(p + 4);
      av[0]=(short)f2bf(x0[0]); av[1]=(short)f2bf(x0[1]); av[2]=(short)f2bf(x0[2]); av[3]=(short)f2bf(x0[3]);
      av[4]=(short)f2bf(x1[0]); av[5]=(short)f2bf(x1[1]); av[6]=(short)f2bf(x1[2]); av[7]=(short)f2bf(x1[3]);
    } else {
      av = *(const s16x8*)(Ab + k0 + sseg * 8);
    }
    {
      const float* p = Bf + k0 + sseg * 8;
      f32x4 x0 = *(const f32x4*)p, x1 = *(const f32x4*)(p + 4);
      bv[0]=(short)f2bf(x0[0]); bv[1]=(short)f2bf(x0[1]); bv[2]=(short)f2bf(x0[2]); bv[3]=(short)f2bf(x0[3]);
      bv[4]=(short)f2bf(x1[0]); bv[5]=(short)f2bf(x1[1]); bv[6]=(short)f2bf(x1[2]); bv[7]=(short)f2bf(x1[3]);
    }
    *(s16x8*)&As[sstore] = av;
    *(s16x8*)&Bs[sstore] = bv;
    __syncthreads();
    s16x8 a0 = *(const s16x8*)&As[aoff0];
    s16x8 a1 = *(const s16x8*)&As[aoff1];
    s16x8 b0 = *(const s16x8*)&Bs[boff0];
    s16x8 b1 = *(const s16x8*)&Bs[boff1];
    acc00 = mfma16(a0, b0, acc00);
    acc01 = mfma16(a0, b1, acc01);
    acc10 = mfma16(a1, b0, acc10);
    acc11 = mfma16(a1, b1, acc11);
    __syncthreads();
  }

  const int mbase = bm0 + wr * 32 + kseg * 4;
  const int nbase = bn0 + wc * 32 + fr;
  auto wr4 = [&](f32x4 v, int m0, int n0) {
    #pragma unroll
    for (int r = 0; r < 4; ++r) {
      float x = v[r];
      if constexpr (MODE == 0)
        ((ushort_t*)Cp)[(size_t)(m0 + r) * 1024 + n0] = f2bf(x + bias1[n0] + bias2[n0]);
      else
        ((float*)Cp)[(size_t)(m0 + r) * 1024 + n0] = x;
    }
  };
  wr4(acc00, mbase,      nbase);
  wr4(acc01, mbase,      nbase + 16);
  wr4(acc10, mbase + 16, nbase);
  wr4(acc11, mbase + 16, nbase + 16);
}

// ---------------------------------------------------------------------------
// Persistent cooperative kernel: the full 64-step recurrence.
// Grid 256 blocks x 512 threads. Per step t:
//   GEMM phase: 768 units (32M x 64N x 1024K) over 256 blocks x 3 teams
//     (2 waves/team; team 3 idles but keeps barrier counts uniform).
//     z1 is split-K into planes p0 (d-part) and p1 (s-part); gates K=1024.
//   grid.sync()
//   attn phase (block b = batch b): z3/softmax/y_tilde, then LSTM pointwise.
//   grid.sync()  [skipped after final step]
// ---------------------------------------------------------------------------
__global__ __launch_bounds__(512) void fused_loop_k(
    ushort_t* __restrict__ dsbf, float* __restrict__ sst,
    const ushort_t* __restrict__ wa1, const ushort_t* __restrict__ whh,
    const ushort_t* __restrict__ z2bf,
    float* __restrict__ z1p0, float* __restrict__ z1p1, float* __restrict__ gates,
    const float* __restrict__ htw, const float* __restrict__ wa3,
    const float* __restrict__ y_seq, const float* __restrict__ Wt,
    const float* __restrict__ btld, const float* __restrict__ W_ih,
    const float* __restrict__ b_ih, const float* __restrict__ b_hh,
    float* __restrict__ betap)
{
  cg::grid_group grid = cg::this_grid();

  const int tid  = threadIdx.x;
  const int wid  = tid >> 6;
  const int lane = tid & 63;
  const int team = wid >> 1;          // 0..3
  const int w2   = wid & 1;
  const int tl   = tid & 127;
  const bool active = (team < 3);
  const int b = blockIdx.x;

  // ---- GEMM unit setup (uniform per team) ----
  const int u  = b * 3 + team;        // 0..767 when active
  const int mt = u / 96;
  const int nu = u % 96;
  const int am0 = mt * 32;
  int akoff, bld, cld, cn0;
  const ushort_t* Bsrc;
  float* Cdst;
  if (nu < 16)      { akoff = 0;    Bsrc = wa1 + (size_t)nu * 64 * 2048;               bld = 2048; Cdst = z1p0;  cld = 1024; cn0 = nu * 64; }
  else if (nu < 32) { akoff = 1024; Bsrc = wa1 + (size_t)(nu - 16) * 64 * 2048 + 1024; bld = 2048; Cdst = z1p1;  cld = 1024; cn0 = (nu - 16) * 64; }
  else              { akoff = 0;    Bsrc = whh + (size_t)(nu - 32) * 64 * 1024;        bld = 1024; Cdst = gates; cld = 4096; cn0 = (nu - 32) * 64; }

  const int arow = tl >> 2, achk = tl & 3;
  const int brow = tl >> 1, bchk0 = (tl & 1) * 2, bchk1 = bchk0 + 1;
  const ushort_t* Abase  = dsbf + (size_t)(am0 + arow) * 2048 + akoff + achk * 8;
  const ushort_t* Bbase0 = Bsrc + (size_t)brow * bld + bchk0 * 8;
  const ushort_t* Bbase1 = Bsrc + (size_t)brow * bld + bchk1 * 8;

  __shared__ ushort_t smem[3 * 3072];   // per team: A 32x32 (1024) + B 64x32 (2048)
  ushort_t* lA = &smem[team < 3 ? team * 3072 : 0];
  ushort_t* lB = lA + 1024;

  const int aSt  = arow * 32 + ((achk ^ (arow & 3)) << 3);
  const int bSt0 = brow * 32 + ((bchk0 ^ (brow & 3)) << 3);
  const int bSt1 = brow * 32 + ((bchk1 ^ (brow & 3)) << 3);

  const int fr = lane & 15, kseg = lane >> 4;
  const int xk = (kseg ^ (fr & 3)) << 3;
  const int aAddr0 = fr * 32 + xk;
  const int aAddr1 = (16 + fr) * 32 + xk;
  const int bAddr0 = (w2 * 32 + fr) * 32 + xk;
  const int bAddr1 = (w2 * 32 + 16 + fr) * 32 + xk;

  __shared__ float zs[64];
  __shared__ float yt_sh;

  for (int t = 0; t < 64; ++t) {
    // ================= GEMM phase =================
    f32x4 acc00 = {0,0,0,0}, acc01 = {0,0,0,0}, acc10 = {0,0,0,0}, acc11 = {0,0,0,0};
    s16x8 avE, b0E, b1E, avO, b0O, b1O;
    if (active) {
      avE = *(const s16x8*)(Abase);
      b0E = *(const s16x8*)(Bbase0);
      b1E = *(const s16x8*)(Bbase1);
    }
    #pragma unroll 1
    for (int kk = 0; kk < 32; kk += 2) {
      if (active) {
        *(s16x8*)&lA[aSt] = avE; *(s16x8*)&lB[bSt0] = b0E; *(s16x8*)&lB[bSt1] = b1E;
      }
      __syncthreads();
      if (active) {
        const int k1 = (kk + 1) * 32;
        avO = *(const s16x8*)(Abase  + k1);
        b0O = *(const s16x8*)(Bbase0 + k1);
        b1O = *(const s16x8*)(Bbase1 + k1);
        s16x8 a0  = *(const s16x8*)&lA[aAddr0];
        s16x8 a1  = *(const s16x8*)&lA[aAddr1];
        s16x8 bb0 = *(const s16x8*)&lB[bAddr0];
        s16x8 bb1 = *(const s16x8*)&lB[bAddr1];
        acc00 = mfma16(a0, bb0, acc00); acc01 = mfma16(a0, bb1, acc01);
        acc10 = mfma16(a1, bb0, acc10); acc11 = mfma16(a1, bb1, acc11);
      }
      __syncthreads();
      if (active) {
        *(s16x8*)&lA[aSt] = avO; *(s16x8*)&lB[bSt0] = b0O; *(s16x8*)&lB[bSt1] = b1O;
      }
      __syncthreads();
      if (active) {
        if (kk + 2 < 32) {
          const int k2 = (kk + 2) * 32;
          avE = *(const s16x8*)(Abase  + k2);
          b0E = *(const s16x8*)(Bbase0 + k2);
          b1E = *(const s16x8*)(Bbase1 + k2);
        }
        s16x8 a0  = *(const s16x8*)&lA[aAddr0];
        s16x8 a1  = *(const s16x8*)&lA[aAddr1];
        s16x8 bb0 = *(const s16x8*)&lB[bAddr0];
        s16x8 bb1 = *(const s16x8*)&lB[bAddr1];
        acc00 = mfma16(a0, bb0, acc00); acc01 = mfma16(a0, bb1, acc01);
        acc10 = mfma16(a1, bb0, acc10); acc11 = mfma16(a1, bb1, acc11);
      }
      __syncthreads();
    }
    if (active) {
      const int mb = am0 + kseg * 4;
      const int nb = cn0 + w2 * 32 + fr;
      #pragma unroll
      for (int r = 0; r < 4; ++r) {
        Cdst[(size_t)(mb + r)      * cld + nb]      = acc00[r];
        Cdst[(size_t)(mb + r)      * cld + nb + 16] = acc01[r];
        Cdst[(size_t)(mb + r + 16) * cld + nb]      = acc10[r];
        Cdst[(size_t)(mb + r + 16) * cld + nb + 16] = acc11[r];
      }
    }
    grid.sync();

    // ================= attention phase =================
    float z1c[16], wc3[16];
    {
      const float* zp0 = z1p0 + (size_t)b * 1024 + lane * 16;
      const float* zp1 = z1p1 + (size_t)b * 1024 + lane * 16;
      const float* wp  = wa3 + lane * 16;
      #pragma unroll
      for (int j = 0; j < 16; j += 4) {
        f32x4 a0 = *(const f32x4*)(zp0 + j);
        f32x4 a1 = *(const f32x4*)(zp1 + j);
        f32x4 c  = *(const f32x4*)(wp + j);
        z1c[j]   = a0[0] + a1[0]; z1c[j+1] = a0[1] + a1[1];
        z1c[j+2] = a0[2] + a1[2]; z1c[j+3] = a0[3] + a1[3];
        wc3[j] = c[0]; wc3[j+1] = c[1]; wc3[j+2] = c[2]; wc3[j+3] = c[3];
      }
    }

    #pragma unroll
    for (int i = 0; i < 8; ++i) {
      const int tt = wid * 8 + i;
      const ushort_t* zp = z2bf + (((size_t)(b * 64 + tt)) << 10) + lane * 16;
      s16x8 v0 = *(const s16x8*)zp;
      s16x8 v1 = *(const s16x8*)(zp + 8);
      float acc = 0.0f;
      #pragma unroll
      for (int j = 0; j < 8; ++j) acc = fmaf(fast_tanh(z1c[j]     + bf2f((ushort_t)v0[j])), wc3[j],     acc);
      #pragma unroll
      for (int j = 0; j < 8; ++j) acc = fmaf(fast_tanh(z1c[8 + j] + bf2f((ushort_t)v1[j])), wc3[8 + j], acc);
      #pragma unroll
      for (int m = 32; m >= 1; m >>= 1) acc += __shfl_xor(acc, m);
      if (lane == 0) zs[tt] = acc;
    }
    __syncthreads();

    if (wid == 0) {
      float v = zs[lane];
      float mx = v;
      #pragma unroll
      for (int m = 32; m >= 1; m >>= 1) mx = fmaxf(mx, __shfl_xor(mx, m));
      float e = __expf(v - mx);
      float sum = e;
      #pragma unroll
      for (int m = 32; m >= 1; m >>= 1) sum += __shfl_xor(sum, m);
      float betav = e * frcp(sum);
      if (t == 63) betap[b * 64 + lane] = betav;
      float a = betav * htw[b * 64 + lane];
      #pragma unroll
      for (int m = 32; m >= 1; m >>= 1) a += __shfl_xor(a, m);
      if (lane == 0) yt_sh = fmaf(Wt[0], y_seq[b * 64 + t], a + btld[0]);
    }
    __syncthreads();

    if (t < 63) {
      const float ytv = yt_sh;
      const float* gb = gates + (size_t)b * 4096;
      #pragma unroll
      for (int r = 0; r < 2; ++r) {
        const int hi = tid + r * 512;
        float gi = gb[hi]        + ytv * W_ih[hi]        + b_ih[hi]        + b_hh[hi];
        float gf = gb[1024 + hi] + ytv * W_ih[1024 + hi] + b_ih[1024 + hi] + b_hh[1024 + hi];
        float gg = gb[2048 + hi] + ytv * W_ih[2048 + hi] + b_ih[2048 + hi] + b_hh[2048 + hi];
        float go = gb[3072 + hi] + ytv * W_ih[3072 + hi] + b_ih[3072 + hi] + b_hh[3072 + hi];
        float so = sst[(size_t)b * 1024 + hi];
        float ig = fast_sig(gi), fg = fast_sig(gf), gt = fast_tanh(gg), og = fast_sig(go);
        float sn = fmaf(fg, so, ig * gt);
        float dn = og * fast_tanh(sn);
        sst[(size_t)b * 1024 + hi] = sn;
        dsbf[(size_t)b * 2048 + hi] = f2bf(dn);
        dsbf[(size_t)b * 2048 + 1024 + hi] = f2bf(sn);
      }
      grid.sync();
    }
  }
}

// htw[b,t] = sum_c h[b,t,c] * W_tilde[1+c]
__global__ __launch_bounds__(256) void htw_k(const float* __restrict__ h, const float* __restrict__ Wt,
                                             float* __restrict__ htw)
{
  const int btx = blockIdx.x;
  const int tid = threadIdx.x;
  const float* hp = h + ((size_t)btx << 10);
  const int c = tid * 4;
  f32x4 hv = *(const f32x4*)(hp + c);
  float acc = hv[0]*Wt[1+c] + hv[1]*Wt[2+c] + hv[2]*Wt[3+c] + hv[3]*Wt[4+c];
  #pragma unroll
  for (int m = 32; m >= 1; m >>= 1) acc += __shfl_xor(acc, m);
  __shared__ float red[4];
  if ((tid & 63) == 0) red[tid >> 6] = acc;
  __syncthreads();
  if (tid == 0) htw[btx] = red[0] + red[1] + red[2] + red[3];
}

// ct[b,c] = sum_t beta[b,t]*h[b,t,c]; assemble dct = [d | ct] bf16
__global__ __launch_bounds__(256) void ct_k(const float* __restrict__ h, const float* __restrict__ beta,
                                            const ushort_t* __restrict__ ds_bf, ushort_t* __restrict__ dct)
{
  const int bid = blockIdx.x;
  const int b = bid >> 2, cb = bid & 3;
  const int c = cb * 256 + threadIdx.x;
  const float* hp = h + ((size_t)b << 16) + c;
  const float* bp = beta + b * 64;
  float acc = 0.0f;
  #pragma unroll 8
  for (int t = 0; t < 64; ++t) acc = fmaf(bp[t], hp[(size_t)t << 10], acc);
  dct[(size_t)b * 2048 + 1024 + c] = f2bf(acc);
  dct[(size_t)b * 2048 + c] = ds_bf[(size_t)b * 2048 + c];
}

// y[b] = sum_n (state[b,n]+b_fc1[n]) * W_fc2[n] + b_fc2   (f32 output)
__global__ __launch_bounds__(256) void head2_k(const float* __restrict__ state, const float* __restrict__ b_fc1,
                                               const float* __restrict__ W_fc2, const float* __restrict__ b_fc2,
                                               float* __restrict__ out)
{
  const int b = blockIdx.x, tid = threadIdx.x;
  const int c = tid * 4;
  f32x4 sv = *(const f32x4*)(state + ((size_t)b << 10) + c);
  f32x4 bv = *(const f32x4*)(b_fc1 + c);
  f32x4 wv = *(const f32x4*)(W_fc2 + c);
  float acc = (sv[0]+bv[0])*wv[0] + (sv[1]+bv[1])*wv[1] + (sv[2]+bv[2])*wv[2] + (sv[3]+bv[3])*wv[3];
  #pragma unroll
  for (int m = 32; m >= 1; m >>= 1) acc += __shfl_xor(acc, m);
  __shared__ float red[4];
  if ((tid & 63) == 0) red[tid >> 6] = acc;
  __syncthreads();
  if (tid == 0) out[b] = red[0] + red[1] + red[2] + red[3] + b_fc2[0];
}

__global__ void cvt_k(const float* __restrict__ in, ushort_t* __restrict__ out, int n)
{
  int i = (blockIdx.x * blockDim.x + threadIdx.x) * 4;
  const int stride = gridDim.x * blockDim.x * 4;
  for (; i < n; i += stride) {
    f32x4 v = *(const f32x4*)(in + i);
    u16x4 o; o[0] = f2bf(v[0]); o[1] = f2bf(v[1]); o[2] = f2bf(v[2]); o[3] = f2bf(v[3]);
    *(u16x4*)(out + i) = o;
  }
}

extern "C" void kernel_launch(void* const* d_in, const int* in_sizes, int n_in,
                              void* d_out, int out_size, void* d_ws, size_t ws_size,
                              hipStream_t stream)
{
  const float* h       = (const float*)d_in[0];
  const float* y_seq   = (const float*)d_in[1];
  const float* W_attn1 = (const float*)d_in[2];
  const float* b_attn1 = (const float*)d_in[3];
  const float* W_attn2 = (const float*)d_in[4];
  const float* b_attn2 = (const float*)d_in[5];
  const float* W_attn3 = (const float*)d_in[6];
  // d_in[7] = b_attn3: softmax shift-invariant, unused
  const float* W_ih    = (const float*)d_in[8];
  const float* W_hh    = (const float*)d_in[9];
  const float* b_ih    = (const float*)d_in[10];
  const float* b_hh    = (const float*)d_in[11];
  const float* W_tilde = (const float*)d_in[12];
  const float* b_tilde = (const float*)d_in[13];
  const float* W_fc1   = (const float*)d_in[14];
  const float* b_fc1   = (const float*)d_in[15];
  const float* W_fc2   = (const float*)d_in[16];
  const float* b_fc2   = (const float*)d_in[17];
  (void)in_sizes; (void)n_in; (void)out_size; (void)ws_size;

  char* ws = (char*)d_ws;
  ushort_t* z2bf   = (ushort_t*)(ws + 0);          // 33554432
  ushort_t* wa1bf  = (ushort_t*)(ws + 33554432);   //  4194304
  ushort_t* whhbf  = (ushort_t*)(ws + 37748736);   //  8388608
  float*    z1p0   = (float*)   (ws + 46137344);   //  1048576
  float*    z1p1   = (float*)   (ws + 47185920);   //  1048576
  float*    gatesp = (float*)   (ws + 48234496);   //  4194304
  ushort_t* dsbf   = (ushort_t*)(ws + 52428800);   //  1048576
  float*    sst    = (float*)   (ws + 53477376);   //  1048576
  float*    htwp   = (float*)   (ws + 54525952);   //    65536
  float*    betap  = (float*)   (ws + 54591488);   //    65536
  ushort_t* dctp   = (ushort_t*)(ws + 54657024);   //  1048576
  float*    statep = (float*)   (ws + 55705600);   //  1048576

  hipMemsetAsync(dsbf, 0, 1048576, stream);
  hipMemsetAsync(sst,  0, 1048576, stream);
  cvt_k<<<dim3(256), dim3(256), 0, stream>>>(W_attn1, wa1bf, 2097152);
  cvt_k<<<dim3(256), dim3(256), 0, stream>>>(W_hh,    whhbf, 4194304);
  htw_k<<<dim3(16384), dim3(256), 0, stream>>>(h, W_tilde, htwp);
  gemm_bt_k<0><<<dim3(256, 16), dim3(256), 0, stream>>>(h, W_attn2, nullptr, z2bf, b_attn1, b_attn2);

  void* kargs[] = {
    (void*)&dsbf, (void*)&sst, (void*)&wa1bf, (void*)&whhbf, (void*)&z2bf,
    (void*)&z1p0, (void*)&z1p1, (void*)&gatesp, (void*)&htwp, (void*)&W_attn3,
    (void*)&y_seq, (void*)&W_tilde, (void*)&b_tilde, (void*)&W_ih, (void*)&b_ih,
    (void*)&b_hh, (void*)&betap
  };
  hipLaunchCooperativeKernel((void*)fused_loop_k, dim3(256), dim3(512), kargs, 0, stream);

  ct_k<<<dim3(1024), dim3(256), 0, stream>>>(h, betap, dsbf, dctp);
  gemm_bt_k<2><<<dim3(4, 16), dim3(256), 0, stream>>>(dctp, W_fc1, nullptr, statep, nullptr, nullptr);
  head2_k<<<dim3(256), dim3(256), 0, stream>>>(statep, b_fc1, W_fc2, b_fc2, (float*)d_out);
}

// Round 4
// 4481.372 us; speedup vs baseline: 1.4402x; 1.4402x over previous
//
#include <hip/hip_runtime.h>
#include <hip/hip_cooperative_groups.h>

typedef unsigned short ushort_t;
typedef __attribute__((ext_vector_type(4))) float f32x4;
typedef __attribute__((ext_vector_type(8))) short s16x8;
typedef __attribute__((ext_vector_type(4))) unsigned short u16x4;
typedef __attribute__((ext_vector_type(8))) __bf16 bf16x8;

#define DEV __device__ __forceinline__

DEV float bf2f(ushort_t u){ union { unsigned int i; float f; } v; v.i = ((unsigned int)u) << 16; return v.f; }
DEV ushort_t f2bf(float f){
  union { float f; unsigned int i; } v; v.f = f;
  unsigned int r = v.i + 0x7FFFu + ((v.i >> 16) & 1u);   // RNE
  return (ushort_t)(r >> 16);
}
DEV float frcp(float x){
#if __has_builtin(__builtin_amdgcn_rcpf)
  return __builtin_amdgcn_rcpf(x);
#else
  return 1.0f / x;
#endif
}
DEV float fast_tanh(float x){
  x = fminf(9.0f, fmaxf(-9.0f, x));
  float e = __expf(2.0f * x);
  return fmaf(-2.0f, frcp(e + 1.0f), 1.0f);
}
DEV float fast_sig(float x){ return frcp(1.0f + __expf(-x)); }

DEV f32x4 mfma16(s16x8 a, s16x8 b, f32x4 c){
  return __builtin_amdgcn_mfma_f32_16x16x32_bf16(
      __builtin_bit_cast(bf16x8, a), __builtin_bit_cast(bf16x8, b), c, 0, 0, 0);
}

// 32-block group barrier: slot is a fresh zeroed counter per (group, barrier#).
// Agent-scope acq_rel add + acquire spin => prior plain stores visible after.
DEV void gbar(unsigned* slot){
  __syncthreads();
  if (threadIdx.x == 0) {
    __hip_atomic_fetch_add(slot, 1u, __ATOMIC_ACQ_REL, __HIP_MEMORY_SCOPE_AGENT);
    while (__hip_atomic_load(slot, __ATOMIC_ACQUIRE, __HIP_MEMORY_SCOPE_AGENT) < 32u) {
      __builtin_amdgcn_s_sleep(2);
    }
  }
  __syncthreads();
}

// ---------------------------------------------------------------------------
// One-shot GEMMs (prologue/epilogue): C[m,n] = sum_k A[m,k]*B[n,k].
// MODE 0: A=h f32, B=W_attn2 f32 -> z2 bf16 (+b_attn1[n]+b_attn2[n])
// MODE 2: A=dct bf16 [256,2048], B=W_fc1 f32 [1024,2048] -> f32 [256,1024]
// ---------------------------------------------------------------------------
template<int MODE>
__global__ __launch_bounds__(256) void gemm_bt_k(
    const void* __restrict__ Ap, const void* __restrict__ Bp,
    void* __restrict__ Cp, const float* __restrict__ bias1, const float* __restrict__ bias2)
{
  const int bm0 = blockIdx.x * 64;
  const int bn0 = blockIdx.y * 64;
  const int tid = threadIdx.x;
  const int srow = tid >> 2, sseg = tid & 3;
  const int wid = tid >> 6, lane = tid & 63;
  const int wr = wid >> 1, wc = wid & 1;
  const int fr = lane & 15, kseg = lane >> 4;

  int K;
  const float* Af = nullptr; const ushort_t* Ab = nullptr;
  const float* Bf = nullptr;
  if constexpr (MODE == 0) {
    K = 1024;
    Af = (const float*)Ap + (size_t)(bm0 + srow) * 1024;
    Bf = (const float*)Bp + (size_t)(bn0 + srow) * 1024;
  } else {
    K = 2048;
    Ab = (const ushort_t*)Ap + (size_t)(bm0 + srow) * 2048;
    Bf = (const float*)Bp + (size_t)(bn0 + srow) * 2048;
  }

  __shared__ ushort_t As[64 * 32];
  __shared__ ushort_t Bs[64 * 32];
  f32x4 acc00 = {0,0,0,0}, acc01 = {0,0,0,0}, acc10 = {0,0,0,0}, acc11 = {0,0,0,0};

  const int sstore = srow * 32 + ((sseg ^ (srow & 3)) << 3);
  const int ar0 = wr * 32 + fr,      ar1 = wr * 32 + 16 + fr;
  const int br0 = wc * 32 + fr,      br1 = wc * 32 + 16 + fr;
  const int aoff0 = ar0 * 32 + ((kseg ^ (ar0 & 3)) << 3);
  const int aoff1 = ar1 * 32 + ((kseg ^ (ar1 & 3)) << 3);
  const int boff0 = br0 * 32 + ((kseg ^ (br0 & 3)) << 3);
  const int boff1 = br1 * 32 + ((kseg ^ (br1 & 3)) << 3);

  for (int k0 = 0; k0 < K; k0 += 32) {
    s16x8 av, bv;
    if constexpr (MODE == 0) {
      const float* p = Af + k0 + sseg * 8;
      f32x4 x0 = *(const f32x4*)p, x1 = *(const f32x4*)(p + 4);
      av[0]=(short)f2bf(x0[0]); av[1]=(short)f2bf(x0[1]); av[2]=(short)f2bf(x0[2]); av[3]=(short)f2bf(x0[3]);
      av[4]=(short)f2bf(x1[0]); av[5]=(short)f2bf(x1[1]); av[6]=(short)f2bf(x1[2]); av[7]=(short)f2bf(x1[3]);
    } else {
      av = *(const s16x8*)(Ab + k0 + sseg * 8);
    }
    {
      const float* p = Bf + k0 + sseg * 8;
      f32x4 x0 = *(const f32x4*)p, x1 = *(const f32x4*)(p + 4);
      bv[0]=(short)f2bf(x0[0]); bv[1]=(short)f2bf(x0[1]); bv[2]=(short)f2bf(x0[2]); bv[3]=(short)f2bf(x0[3]);
      bv[4]=(short)f2bf(x1[0]); bv[5]=(short)f2bf(x1[1]); bv[6]=(short)f2bf(x1[2]); bv[7]=(short)f2bf(x1[3]);
    }
    *(s16x8*)&As[sstore] = av;
    *(s16x8*)&Bs[sstore] = bv;
    __syncthreads();
    s16x8 a0 = *(const s16x8*)&As[aoff0];
    s16x8 a1 = *(const s16x8*)&As[aoff1];
    s16x8 b0 = *(const s16x8*)&Bs[boff0];
    s16x8 b1 = *(const s16x8*)&Bs[boff1];
    acc00 = mfma16(a0, b0, acc00);
    acc01 = mfma16(a0, b1, acc01);
    acc10 = mfma16(a1, b0, acc10);
    acc11 = mfma16(a1, b1, acc11);
    __syncthreads();
  }

  const int mbase = bm0 + wr * 32 + kseg * 4;
  const int nbase = bn0 + wc * 32 + fr;
  auto wr4 = [&](f32x4 v, int m0, int n0) {
    #pragma unroll
    for (int r = 0; r < 4; ++r) {
      float x = v[r];
      if constexpr (MODE == 0)
        ((ushort_t*)Cp)[(size_t)(m0 + r) * 1024 + n0] = f2bf(x + bias1[n0] + bias2[n0]);
      else
        ((float*)Cp)[(size_t)(m0 + r) * 1024 + n0] = x;
    }
  };
  wr4(acc00, mbase,      nbase);
  wr4(acc01, mbase,      nbase + 16);
  wr4(acc10, mbase + 16, nbase);
  wr4(acc11, mbase + 16, nbase + 16);
}

// ---------------------------------------------------------------------------
// Persistent recurrence, XCD-group structure. 256 blocks x 512 thr.
// group g = bid%8 (XCD-local under round-robin; perf heuristic only),
// member j = bid/8, owned batch b = g*32+j.
// Per step: stage group's ds[32x2048]bf16 into LDS (swizzled); 6 waves/block
// each compute one 32Mx32Nx1024K tile (z1 split-K planes + gates), B from
// global; group barrier; per-block attn+softmax+y_tilde+LSTM for batch b;
// group barrier. No grid.sync anywhere.
// ---------------------------------------------------------------------------
__global__ __launch_bounds__(512) void fused_loop2_k(
    ushort_t* __restrict__ dsbf, float* __restrict__ sst,
    const ushort_t* __restrict__ wa1, const ushort_t* __restrict__ whh,
    const ushort_t* __restrict__ z2bf,
    float* __restrict__ z1p0, float* __restrict__ z1p1, float* __restrict__ gates,
    const float* __restrict__ htw, const float* __restrict__ wa3,
    const float* __restrict__ y_seq, const float* __restrict__ Wt,
    const float* __restrict__ btld, const float* __restrict__ W_ih,
    const float* __restrict__ b_ih, const float* __restrict__ b_hh,
    float* __restrict__ betap, unsigned* __restrict__ bars)
{
  const int tid  = threadIdx.x;
  const int w    = tid >> 6;
  const int lane = tid & 63;
  const int fr   = lane & 15, kseg = lane >> 4;
  const int g    = blockIdx.x & 7;
  const int j    = blockIdx.x >> 3;
  const int b    = g * 32 + j;
  unsigned* gbars = bars + g * 256;

  __shared__ ushort_t As[32 * 2048];   // 128 KiB: group's [d|s] bf16, swizzled
  __shared__ float zs[64];
  __shared__ float yt_sh;

  // ---- per-wave GEMM tile (gw = w*32+j; 192 tiles; waves 6,7 idle) ----
  const int gw = w * 32 + j;
  float* Cd = z1p0; const ushort_t* Bb = wa1;
  int n0 = 0, cld = 1024, koff = 0; size_t ldb = 2048;
  if (gw < 32)      { Cd = z1p0;  n0 = gw * 32;        Bb = wa1; ldb = 2048; koff = 0;    cld = 1024; }
  else if (gw < 64) { Cd = z1p1;  n0 = (gw - 32) * 32; Bb = wa1; ldb = 2048; koff = 1024; cld = 1024; }
  else              { Cd = gates; n0 = (gw - 64) * 32; Bb = whh; ldb = 1024; koff = 0;    cld = 4096; }
  const ushort_t* B0p = Bb + (size_t)(n0 + fr) * ldb + koff + kseg * 8;
  const ushort_t* B1p = Bb + (size_t)(n0 + 16 + fr) * ldb + koff + kseg * 8;
  const int cbase = (koff >> 3) + kseg;
  const ushort_t* stage_src = dsbf + (size_t)(g * 32) * 2048;

  for (int t = 0; t < 64; ++t) {
    // ---- stage A (group's ds) into LDS, 16B chunks, XOR-swizzled ----
    #pragma unroll
    for (int it = 0; it < 16; ++it) {
      const int i = tid + it * 512;          // 0..8191
      const int row = i >> 8, c = i & 255;
      s16x8 v = *(const s16x8*)(stage_src + (size_t)row * 2048 + c * 8);
      *(s16x8*)&As[row * 2048 + ((c ^ (row & 7)) << 3)] = v;
    }
    __syncthreads();

    // ---- GEMM: 32Mx32Nx1024K per busy wave ----
    if (w < 6) {
      f32x4 acc00 = {0,0,0,0}, acc01 = {0,0,0,0}, acc10 = {0,0,0,0}, acc11 = {0,0,0,0};
      s16x8 b0 = *(const s16x8*)B0p;
      s16x8 b1 = *(const s16x8*)B1p;
      #pragma unroll 4
      for (int kk = 0; kk < 32; ++kk) {
        const int ch = cbase + kk * 4;
        const int sw = ((ch ^ (fr & 7)) << 3);
        s16x8 a0 = *(const s16x8*)&As[fr * 2048 + sw];
        s16x8 a1 = *(const s16x8*)&As[(16 + fr) * 2048 + sw];
        s16x8 nb0 = b0, nb1 = b1;
        if (kk < 31) {
          nb0 = *(const s16x8*)(B0p + (kk + 1) * 32);
          nb1 = *(const s16x8*)(B1p + (kk + 1) * 32);
        }
        acc00 = mfma16(a0, b0, acc00);
        acc01 = mfma16(a0, b1, acc01);
        acc10 = mfma16(a1, b0, acc10);
        acc11 = mfma16(a1, b1, acc11);
        b0 = nb0; b1 = nb1;
      }
      const int gm = g * 32 + kseg * 4;
      const int gn = n0 + fr;
      #pragma unroll
      for (int r = 0; r < 4; ++r) {
        Cd[(size_t)(gm + r)      * cld + gn]      = acc00[r];
        Cd[(size_t)(gm + r)      * cld + gn + 16] = acc01[r];
        Cd[(size_t)(gm + r + 16) * cld + gn]      = acc10[r];
        Cd[(size_t)(gm + r + 16) * cld + gn + 16] = acc11[r];
      }
    }
    gbar(&gbars[t * 2]);          // z1/gates visible group-wide

    // ---- attention for batch b ----
    float z1c[16], wc3[16];
    {
      const float* zp0 = z1p0 + (size_t)b * 1024 + lane * 16;
      const float* zp1 = z1p1 + (size_t)b * 1024 + lane * 16;
      const float* wp  = wa3 + lane * 16;
      #pragma unroll
      for (int q = 0; q < 16; q += 4) {
        f32x4 a0 = *(const f32x4*)(zp0 + q);
        f32x4 a1 = *(const f32x4*)(zp1 + q);
        f32x4 c  = *(const f32x4*)(wp + q);
        z1c[q]   = a0[0] + a1[0]; z1c[q+1] = a0[1] + a1[1];
        z1c[q+2] = a0[2] + a1[2]; z1c[q+3] = a0[3] + a1[3];
        wc3[q] = c[0]; wc3[q+1] = c[1]; wc3[q+2] = c[2]; wc3[q+3] = c[3];
      }
    }
    #pragma unroll
    for (int i = 0; i < 8; ++i) {
      const int tt = w * 8 + i;
      const ushort_t* zp = z2bf + (((size_t)(b * 64 + tt)) << 10) + lane * 16;
      s16x8 v0 = *(const s16x8*)zp;
      s16x8 v1 = *(const s16x8*)(zp + 8);
      float acc = 0.0f;
      #pragma unroll
      for (int q = 0; q < 8; ++q) acc = fmaf(fast_tanh(z1c[q]     + bf2f((ushort_t)v0[q])), wc3[q],     acc);
      #pragma unroll
      for (int q = 0; q < 8; ++q) acc = fmaf(fast_tanh(z1c[8 + q] + bf2f((ushort_t)v1[q])), wc3[8 + q], acc);
      #pragma unroll
      for (int m = 32; m >= 1; m >>= 1) acc += __shfl_xor(acc, m);
      if (lane == 0) zs[tt] = acc;
    }
    __syncthreads();

    if (w == 0) {
      float v = zs[lane];
      float mx = v;
      #pragma unroll
      for (int m = 32; m >= 1; m >>= 1) mx = fmaxf(mx, __shfl_xor(mx, m));
      float e = __expf(v - mx);
      float sum = e;
      #pragma unroll
      for (int m = 32; m >= 1; m >>= 1) sum += __shfl_xor(sum, m);
      float betav = e * frcp(sum);
      if (t == 63) betap[b * 64 + lane] = betav;
      float a = betav * htw[b * 64 + lane];
      #pragma unroll
      for (int m = 32; m >= 1; m >>= 1) a += __shfl_xor(a, m);
      if (lane == 0) yt_sh = fmaf(Wt[0], y_seq[b * 64 + t], a + btld[0]);
    }
    __syncthreads();

    if (t < 63) {
      const float ytv = yt_sh;
      const float* gb = gates + (size_t)b * 4096;
      #pragma unroll
      for (int r = 0; r < 2; ++r) {
        const int hi = tid + r * 512;
        float gi = gb[hi]        + ytv * W_ih[hi]        + b_ih[hi]        + b_hh[hi];
        float gf = gb[1024 + hi] + ytv * W_ih[1024 + hi] + b_ih[1024 + hi] + b_hh[1024 + hi];
        float gg = gb[2048 + hi] + ytv * W_ih[2048 + hi] + b_ih[2048 + hi] + b_hh[2048 + hi];
        float go = gb[3072 + hi] + ytv * W_ih[3072 + hi] + b_ih[3072 + hi] + b_hh[3072 + hi];
        float so = sst[(size_t)b * 1024 + hi];
        float ig = fast_sig(gi), fg = fast_sig(gf), gt = fast_tanh(gg), og = fast_sig(go);
        float sn = fmaf(fg, so, ig * gt);
        float dn = og * fast_tanh(sn);
        sst[(size_t)b * 1024 + hi] = sn;
        dsbf[(size_t)b * 2048 + hi] = f2bf(dn);
        dsbf[(size_t)b * 2048 + 1024 + hi] = f2bf(sn);
      }
      gbar(&gbars[t * 2 + 1]);    // ds visible before next step's staging
    }
  }
}

// htw[b,t] = sum_c h[b,t,c] * W_tilde[1+c]
__global__ __launch_bounds__(256) void htw_k(const float* __restrict__ h, const float* __restrict__ Wt,
                                             float* __restrict__ htw)
{
  const int btx = blockIdx.x;
  const int tid = threadIdx.x;
  const float* hp = h + ((size_t)btx << 10);
  const int c = tid * 4;
  f32x4 hv = *(const f32x4*)(hp + c);
  float acc = hv[0]*Wt[1+c] + hv[1]*Wt[2+c] + hv[2]*Wt[3+c] + hv[3]*Wt[4+c];
  #pragma unroll
  for (int m = 32; m >= 1; m >>= 1) acc += __shfl_xor(acc, m);
  __shared__ float red[4];
  if ((tid & 63) == 0) red[tid >> 6] = acc;
  __syncthreads();
  if (tid == 0) htw[btx] = red[0] + red[1] + red[2] + red[3];
}

// ct[b,c] = sum_t beta[b,t]*h[b,t,c]; assemble dct = [d | ct] bf16
__global__ __launch_bounds__(256) void ct_k(const float* __restrict__ h, const float* __restrict__ beta,
                                            const ushort_t* __restrict__ ds_bf, ushort_t* __restrict__ dct)
{
  const int bid = blockIdx.x;
  const int b = bid >> 2, cb = bid & 3;
  const int c = cb * 256 + threadIdx.x;
  const float* hp = h + ((size_t)b << 16) + c;
  const float* bp = beta + b * 64;
  float acc = 0.0f;
  #pragma unroll 8
  for (int t = 0; t < 64; ++t) acc = fmaf(bp[t], hp[(size_t)t << 10], acc);
  dct[(size_t)b * 2048 + 1024 + c] = f2bf(acc);
  dct[(size_t)b * 2048 + c] = ds_bf[(size_t)b * 2048 + c];
}

// y[b] = sum_n (state[b,n]+b_fc1[n]) * W_fc2[n] + b_fc2   (f32 output)
__global__ __launch_bounds__(256) void head2_k(const float* __restrict__ state, const float* __restrict__ b_fc1,
                                               const float* __restrict__ W_fc2, const float* __restrict__ b_fc2,
                                               float* __restrict__ out)
{
  const int b = blockIdx.x, tid = threadIdx.x;
  const int c = tid * 4;
  f32x4 sv = *(const f32x4*)(state + ((size_t)b << 10) + c);
  f32x4 bv = *(const f32x4*)(b_fc1 + c);
  f32x4 wv = *(const f32x4*)(W_fc2 + c);
  float acc = (sv[0]+bv[0])*wv[0] + (sv[1]+bv[1])*wv[1] + (sv[2]+bv[2])*wv[2] + (sv[3]+bv[3])*wv[3];
  #pragma unroll
  for (int m = 32; m >= 1; m >>= 1) acc += __shfl_xor(acc, m);
  __shared__ float red[4];
  if ((tid & 63) == 0) red[tid >> 6] = acc;
  __syncthreads();
  if (tid == 0) out[b] = red[0] + red[1] + red[2] + red[3] + b_fc2[0];
}

__global__ void cvt_k(const float* __restrict__ in, ushort_t* __restrict__ out, int n)
{
  int i = (blockIdx.x * blockDim.x + threadIdx.x) * 4;
  const int stride = gridDim.x * blockDim.x * 4;
  for (; i < n; i += stride) {
    f32x4 v = *(const f32x4*)(in + i);
    u16x4 o; o[0] = f2bf(v[0]); o[1] = f2bf(v[1]); o[2] = f2bf(v[2]); o[3] = f2bf(v[3]);
    *(u16x4*)(out + i) = o;
  }
}

extern "C" void kernel_launch(void* const* d_in, const int* in_sizes, int n_in,
                              void* d_out, int out_size, void* d_ws, size_t ws_size,
                              hipStream_t stream)
{
  const float* h       = (const float*)d_in[0];
  const float* y_seq   = (const float*)d_in[1];
  const float* W_attn1 = (const float*)d_in[2];
  const float* b_attn1 = (const float*)d_in[3];
  const float* W_attn2 = (const float*)d_in[4];
  const float* b_attn2 = (const float*)d_in[5];
  const float* W_attn3 = (const float*)d_in[6];
  // d_in[7] = b_attn3: softmax shift-invariant, unused
  const float* W_ih    = (const float*)d_in[8];
  const float* W_hh    = (const float*)d_in[9];
  const float* b_ih    = (const float*)d_in[10];
  const float* b_hh    = (const float*)d_in[11];
  const float* W_tilde = (const float*)d_in[12];
  const float* b_tilde = (const float*)d_in[13];
  const float* W_fc1   = (const float*)d_in[14];
  const float* b_fc1   = (const float*)d_in[15];
  const float* W_fc2   = (const float*)d_in[16];
  const float* b_fc2   = (const float*)d_in[17];
  (void)in_sizes; (void)n_in; (void)out_size; (void)ws_size;

  char* ws = (char*)d_ws;
  ushort_t* z2bf   = (ushort_t*)(ws + 0);          // 33554432
  ushort_t* wa1bf  = (ushort_t*)(ws + 33554432);   //  4194304
  ushort_t* whhbf  = (ushort_t*)(ws + 37748736);   //  8388608
  float*    z1p0   = (float*)   (ws + 46137344);   //  1048576
  float*    z1p1   = (float*)   (ws + 47185920);   //  1048576
  float*    gatesp = (float*)   (ws + 48234496);   //  4194304
  ushort_t* dsbf   = (ushort_t*)(ws + 52428800);   //  1048576
  float*    sst    = (float*)   (ws + 53477376);   //  1048576
  float*    htwp   = (float*)   (ws + 54525952);   //    65536
  float*    betap  = (float*)   (ws + 54591488);   //    65536
  ushort_t* dctp   = (ushort_t*)(ws + 54657024);   //  1048576
  float*    statep = (float*)   (ws + 55705600);   //  1048576
  unsigned* bars   = (unsigned*)(ws + 56754176);   //     8192: [8 groups][256 slots]

  hipMemsetAsync(dsbf, 0, 1048576, stream);
  hipMemsetAsync(sst,  0, 1048576, stream);
  hipMemsetAsync(bars, 0, 8192, stream);
  cvt_k<<<dim3(256), dim3(256), 0, stream>>>(W_attn1, wa1bf, 2097152);
  cvt_k<<<dim3(256), dim3(256), 0, stream>>>(W_hh,    whhbf, 4194304);
  htw_k<<<dim3(16384), dim3(256), 0, stream>>>(h, W_tilde, htwp);
  gemm_bt_k<0><<<dim3(256, 16), dim3(256), 0, stream>>>(h, W_attn2, z2bf, b_attn1, b_attn2);

  void* kargs[] = {
    (void*)&dsbf, (void*)&sst, (void*)&wa1bf, (void*)&whhbf, (void*)&z2bf,
    (void*)&z1p0, (void*)&z1p1, (void*)&gatesp, (void*)&htwp, (void*)&W_attn3,
    (void*)&y_seq, (void*)&W_tilde, (void*)&b_tilde, (void*)&W_ih, (void*)&b_ih,
    (void*)&b_hh, (void*)&betap, (void*)&bars
  };
  hipLaunchCooperativeKernel((void*)fused_loop2_k, dim3(256), dim3(512), kargs, 0, stream);

  ct_k<<<dim3(1024), dim3(256), 0, stream>>>(h, betap, dsbf, dctp);
  gemm_bt_k<2><<<dim3(4, 16), dim3(256), 0, stream>>>(dctp, W_fc1, statep, nullptr, nullptr);
  head2_k<<<dim3(256), dim3(256), 0, stream>>>(statep, b_fc1, W_fc2, b_fc2, (float*)d_out);
}